// Round 8
// baseline (137.587 us; speedup 1.0000x reference)
//
#include <hip/hip_runtime.h>
#include <math.h>

#define NF       2048
#define NC       10
#define THREADS  256

// ext_vector floats -> packed fp32 VOP3P (v_pk_add_f32 / v_pk_fma_f32).
typedef float f2 __attribute__((ext_vector_type(2)));
typedef float f4 __attribute__((ext_vector_type(4)));

__device__ __forceinline__ f2 mk2(float a, float b){ f2 r; r.x=a; r.y=b; return r; }
__device__ __forceinline__ f2 cmul(f2 a, f2 b){
    f2 t = mk2(a.x, a.x) * b;
    return mk2(a.y, a.y) * mk2(-b.y, b.x) + t;
}
__device__ __forceinline__ f2 mul_mi(f2 d){ return mk2(d.y, -d.x); }  // d * (-i)
__device__ __forceinline__ f2 mul_w1(f2 d){                            // d * exp(-i*pi/4)
    const float C = 0.70710678118654752f;
    return (d + mk2(d.y, -d.x)) * mk2(C, C);
}
__device__ __forceinline__ f2 mul_w3(f2 d){                            // d * exp(-3i*pi/4)
    const float C = 0.70710678118654752f;
    return (mk2(d.y, -d.y) - mk2(d.x, d.x)) * mk2(C, C);
}

// Universal layout rule: position p lives at address p ^ (((p>>4)&7)<<1)
// (flat 2048 domain and per-wave 512 domain use the same formula; the mask
// depends only on bits 4-6 and lands in bits 1-3, so +256m/+512k offsets and
// region bases fold to base+immediate).
__device__ __forceinline__ int swz(int i){ return i ^ (((i >> 4) & 7) << 1); }

// Butterfly all-reduce across the 64-lane wave (sum lands in every lane).
__device__ __forceinline__ f2 wred(f2 v){
    #pragma unroll
    for (int m = 32; m >= 1; m >>= 1) {
        f2 o;
        o.x = __shfl_xor(v.x, m, 64);
        o.y = __shfl_xor(v.y, m, 64);
        v = v + o;
    }
    return v;
}

// Cross-wave radix-4 + twiddle (outer stage of N = 4 x 512 Cooley-Tukey),
// in-place. Thread handles n2 = tid and tid+256; its READ set (flat
// positions n2+512*n1) equals its WRITE set (region k1, position n2) exactly
// -> per-thread-private addresses -> entry barrier only, no mid barrier.
// Output: region[k1][n2] = w2048^(n2*k1) * sum_n1 z[512*n1+n2] * W4^(n1*k1).
__device__ __forceinline__ void stepA(f2* __restrict__ A_,
                                      const f2* __restrict__ twl,
                                      int tid, int fb)
{
    __syncthreads();
    f2 a0 = A_[fb      ], a1 = A_[fb +  512], a2 = A_[fb + 1024], a3 = A_[fb + 1536];
    f2 b0 = A_[fb + 256], b1 = A_[fb +  768], b2 = A_[fb + 1280], b3 = A_[fb + 1792];
    f2 wa = twl[tid], wb = twl[tid + 256];
    {
        f2 s0 = a0+a2, s1 = a1+a3, d0 = a0-a2, d1 = mul_mi(a1-a3);
        f2 w2 = cmul(wa,wa), w3 = cmul(w2,wa);
        A_[fb       ] = s0 + s1;
        A_[fb +  512] = cmul(d0 + d1, wa);
        A_[fb + 1024] = cmul(s0 - s1, w2);
        A_[fb + 1536] = cmul(d0 - d1, w3);
    }
    {
        f2 s0 = b0+b2, s1 = b1+b3, d0 = b0-b2, d1 = mul_mi(b1-b3);
        f2 w2 = cmul(wb,wb), w3 = cmul(w2,wb);
        A_[fb +  256] = s0 + s1;
        A_[fb +  768] = cmul(d0 + d1, wb);
        A_[fb + 1280] = cmul(s0 - s1, w2);
        A_[fb + 1792] = cmul(d0 - d1, w3);
    }
}

// Wave-local radix-8 Stockham stage of the per-wave FFT-512, in-place in the
// wave's private 512-element region, NO barriers (every store value depends
// on all 8 loads -> issue order forced; DS ops execute in order per wave).
// STAGE=1: S=1 (tw = w512^ln), STAGE=2: S=8 (tw = w512^(8h)), STAGE=3: S=64
// (twiddle-free, natural-order output).
template<int STAGE>
__device__ __forceinline__ void wlstage(f2* __restrict__ A_,
                                        const f2* __restrict__ twl,
                                        const f2* __restrict__ tw4,
                                        int ln, int RB, int rb0, int rb1)
{
    f2 a0 = A_[rb0      ], a1 = A_[rb1 +  64];
    f2 a2 = A_[rb0 + 128], a3 = A_[rb1 + 192];
    f2 a4 = A_[rb0 + 256], a5 = A_[rb1 + 320];
    f2 a6 = A_[rb0 + 384], a7 = A_[rb1 + 448];
    f2 u0 = a0+a4, u1 = a0-a4, u2 = a1+a5, u3 = mul_w1(a1-a5);
    f2 u4 = a2+a6, u5 = mul_mi(a2-a6), u6 = a3+a7, u7 = mul_w3(a3-a7);
    f2 v0 = u0+u4, v2 = u0-u4, v1 = u1+u5, v3 = u1-u5;
    f2 v4 = u2+u6, v6 = mul_mi(u2-u6), v5 = u3+u7, v7 = mul_mi(u3-u7);
    f2 y0 = v0+v4, y4 = v0-v4, y1 = v1+v5, y5 = v1-v5;
    f2 y2 = v2+v6, y6 = v2-v6, y3 = v3+v7, y7 = v3-v7;
    if constexpr (STAGE != 3) {
        f2 w1 = (STAGE == 1) ? tw4[ln] : twl[32*(ln>>3)];
        f2 w2 = cmul(w1,w1), w3 = cmul(w2,w1), w4 = cmul(w2,w2);
        f2 w5 = cmul(w4,w1), w6 = cmul(w4,w2), w7 = cmul(w4,w3);
        y1 = cmul(y1,w1); y2 = cmul(y2,w2); y3 = cmul(y3,w3); y4 = cmul(y4,w4);
        y5 = cmul(y5,w5); y6 = cmul(y6,w6); y7 = cmul(y7,w7);
    }
    if constexpr (STAGE == 1) {
        // position 8*ln + k at swz -> (8ln ^ mask) ^ k ; adjacent pairs -> b128
        const int wb = RB + ((8*ln) ^ (((ln>>1)&7)<<1));
        f4 o;
        o.lo = y0; o.hi = y1; *(f4*)&A_[wb    ] = o;
        o.lo = y2; o.hi = y3; *(f4*)&A_[wb ^ 2] = o;
        o.lo = y4; o.hi = y5; *(f4*)&A_[wb ^ 4] = o;
        o.lo = y6; o.hi = y7; *(f4*)&A_[wb ^ 6] = o;
    } else if constexpr (STAGE == 2) {
        const int bi = (ln & 7) + 64*(ln >> 3);       // q + 64h
        #define ST2(K, Y) { int wi = bi + 8*(K); wi ^= ((wi>>4)&7)<<1; A_[RB + wi] = Y; }
        ST2(0,y0) ST2(1,y1) ST2(2,y2) ST2(3,y3)
        ST2(4,y4) ST2(5,y5) ST2(6,y6) ST2(7,y7)
        #undef ST2
    } else {
        // position ln + 64k -> same address family as the reads
        A_[rb0      ] = y0;  A_[rb1 +  64] = y1;
        A_[rb0 + 128] = y2;  A_[rb1 + 192] = y3;
        A_[rb0 + 256] = y4;  A_[rb1 + 320] = y5;
        A_[rb0 + 384] = y6;  A_[rb1 + 448] = y7;
    }
}

// Fully fused single kernel: no workspace, no cross-kernel state.
__global__ __launch_bounds__(THREADS, 8) void vpc_kernel(
        const float* __restrict__ x, const float* __restrict__ w,
        float* __restrict__ out)
{
    __shared__ __align__(16) f2 A[NF];
    __shared__ __align__(16) f2 twl[512];    // w2048^j, j<512
    __shared__ __align__(16) f2 tw4[64];     // w512^j = w2048^(4j), j<64
    __shared__ float smax[NC];
    const int tid = threadIdx.x;
    const int ln  = tid & 63;
    const int wvi = tid >> 6;                // wave index = outer digit k1
    const int row = blockIdx.x;
    const int RB  = wvi << 9;                // wave region base
    const int sl  = ln ^ (((ln>>4)&3)<<1);   // swz(ln), ln<64
    const int rb0 = RB + sl;
    const int rb1 = RB + (sl ^ 8);
    const int fb  = swz(tid);

    // Twiddle tables (per block; no cross-kernel state allowed).
    {
        float s, c;
        __sincosf(-(float)tid * (float)(M_PI/1024.0), &s, &c);
        twl[tid] = mk2(c, s);
        __sincosf(-(float)(tid + 256) * (float)(M_PI/1024.0), &s, &c);
        twl[tid + 256] = mk2(c, s);
        if (tid < 64) {
            __sincosf(-(float)(4*tid) * (float)(M_PI/1024.0), &s, &c);
            tw4[tid] = mk2(c, s);
        }
    }

    // Layer 1: z = exp(i(x+w0)), adjacent-pair butterfly (uniform scales all
    // cancel in the im/|z| readout, so they are dropped throughout).
    const f4* xr4 = (const f4*)(x + (size_t)row * NF);
    const f4* wr4 = (const f4*)w;
    #pragma unroll
    for (int i = 0; i < 2; ++i) {
        const int g = tid + 256*i;
        f4 xv  = xr4[g];
        f4 wv4 = wr4[g];
        float s0,c0,s1,c1,s2,c2,s3,c3;
        __sincosf(xv.x + wv4.x, &s0, &c0);
        __sincosf(xv.y + wv4.y, &s1, &c1);
        __sincosf(xv.z + wv4.z, &s2, &c2);
        __sincosf(xv.w + wv4.w, &s3, &c3);
        f2 z0 = mk2(c0,s0), z1 = mk2(c1,s1), z2 = mk2(c2,s2), z3 = mk2(c3,s3);
        f4 o0; o0.lo = z0+z1; o0.hi = z0-z1;
        f4 o1; o1.lo = z2+z3; o1.hi = z2-z3;
        *(f4*)&A[swz(4*g)]     = o0;
        *(f4*)&A[swz(4*g + 2)] = o1;
    }

    // ===== FFT1: outer radix-4 (cross-wave) + per-wave FFT-512 =====
    stepA(A, twl, tid, fb);            // B1 = entry barrier inside
    __syncthreads();                   // B2: all region writes visible
    wlstage<1>(A, twl, tw4, ln, RB, rb0, rb1);
    __builtin_amdgcn_sched_barrier(0); // pin stage order (rule-18 caution)
    wlstage<2>(A, twl, tw4, ln, RB, rb0, rb1);
    __builtin_amdgcn_sched_barrier(0);
    wlstage<3>(A, twl, tw4, ln, RB, rb0, rb1);
    // region[k1][k2] now holds FFT1 bin (k1 + 4*k2)

    // ===== Layer 2: rotate by exp(i*w1) + adjacent-pair butterfly =====
    // pair m = tid + 256*i: bins (2m, 2m+1) live in regions k1=2*(tid&1),
    // k1+1 at k2 = (tid>>1) + 128*i. Writes go back to flat natural order.
    __syncthreads();                   // B3: wave-local FFT-512s complete
    const int pb0 = ((tid & 1) << 10) + swz(tid >> 1);
    f2 pa0 = A[pb0      ], qa0 = A[pb0 + 512];
    f2 pa1 = A[pb0 + 128], qa1 = A[pb0 + 640];
    f2 pa2 = A[pb0 + 256], qa2 = A[pb0 + 768];
    f2 pa3 = A[pb0 + 384], qa3 = A[pb0 + 896];
    __syncthreads();                   // B4: all reads done before any write
    {
        const f2* w1r = (const f2*)(w + NF);
        const int wb2 = swz(2*tid);
        #define ROT(I, PA, QA) { \
            f2 wv2 = w1r[tid + 256*(I)]; \
            float ss0, cc0, ss1, cc1; \
            __sincosf(wv2.x, &ss0, &cc0); \
            __sincosf(wv2.y, &ss1, &cc1); \
            f2 za = cmul(PA, mk2(cc0, ss0)); \
            f2 zb = cmul(QA, mk2(cc1, ss1)); \
            f4 o; o.lo = za + zb; o.hi = za - zb; \
            *(f4*)&A[wb2 + 512*(I)] = o; }
        ROT(0, pa0, qa0) ROT(1, pa1, qa1) ROT(2, pa2, qa2) ROT(3, pa3, qa3)
        #undef ROT
    }

    // ===== FFT2 (pruned to bins 0..9) =====
    stepA(A, twl, tid, fb);            // B5 = entry barrier inside
    __syncthreads();                   // B6
    {
        // Per-lane partial DFT-8 (stage1 of the wave's FFT-512): only y0,y1,y2
        // feed output bins k1+4*k2, k2<3. X[k2] = sum over lanes of y_k2
        // (stage2 y0 + final y0 collapse into a plain 64-term sum) -> pure
        // register wave-reduction, no LDS round-trip.
        f2 a0 = A[rb0      ], a1 = A[rb1 +  64];
        f2 a2 = A[rb0 + 128], a3 = A[rb1 + 192];
        f2 a4 = A[rb0 + 256], a5 = A[rb1 + 320];
        f2 a6 = A[rb0 + 384], a7 = A[rb1 + 448];
        f2 e04 = a0+a4, e26 = a2+a6, e15 = a1+a5, e37 = a3+a7;
        f2 y0 = (e04 + e26) + (e15 + e37);
        f2 u1 = a0-a4, u3 = mul_w1(a1-a5), u5 = mul_mi(a2-a6), u7 = mul_w3(a3-a7);
        f2 W  = tw4[ln];
        f2 y1 = cmul((u1+u5) + (u3+u7), W);
        f2 y2 = cmul((e04 - e26) + mul_mi(e15 - e37), cmul(W, W));
        y0 = wred(y0); y1 = wred(y1); y2 = wred(y2);
        if (ln < 3) {
            f2 X = (ln == 0) ? y0 : ((ln == 1) ? y1 : y2);
            int bin = wvi + 4*ln;
            if (bin < NC) {
                float mag = sqrtf(X.x*X.x + X.y*X.y);
                smax[bin] = 5.0f * X.y / fmaxf(mag, 1e-30f);
            }
        }
    }
    __syncthreads();                   // B7
    if (tid < NC) {
        float l  = smax[tid];
        float mx = smax[0];
        #pragma unroll
        for (int j = 1; j < NC; ++j) mx = fmaxf(mx, smax[j]);
        float s = 0.f;
        #pragma unroll
        for (int j = 0; j < NC; ++j) s += __expf(smax[j] - mx);
        out[(size_t)row * NC + tid] = __expf(l - mx) / s;
    }
}

extern "C" void kernel_launch(void* const* d_in, const int* in_sizes, int n_in,
                              void* d_out, int out_size, void* d_ws, size_t ws_size,
                              hipStream_t stream) {
    const float* x = (const float*)d_in[0];   // (8192, 2048) f32
    const float* w = (const float*)d_in[1];   // (4096,) f32
    float* out = (float*)d_out;               // (8192, 10) f32
    (void)d_ws; (void)ws_size;                // intentionally unused

    vpc_kernel<<<8192, THREADS, 0, stream>>>(x, w, out);
}